// Round 6
// baseline (552.695 us; speedup 1.0000x reference)
//
#include <hip/hip_runtime.h>
#include <math.h>

#define GLN_EPS 1e-6f
#define NW 8                    // waves per block
#define BLOCK (NW * 64)         // 512 threads
#define CCH 256                 // channels (fixed by problem)
#define C4 (CCH / 4)            // 64 float4 per row == one wave
#define RPW 16                  // rows per wave, fast path (cnt == NW*RPW == 128)
#define RCAP 2048               // rowmean cache rows (generic path; aliases s_lds space)

// pin a float4 into VGPRs / keep live across the barrier (prevents re-load sinking)
#define KEEP4(f) asm volatile("" : "+v"((f).x), "+v"((f).y), "+v"((f).z), "+v"((f).w))

// ---- dynamic-LDS carve (bytes) ----
#define OFF_SLDS   0
#define SZ_SLDS    (128 * C4 * 16)           // 131072: s tile [128 rows][64 float4] (fast path)
#define OFF_CSUM   (OFF_SLDS + SZ_SLDS)
#define SZ_CSUM    (NW * C4 * 16)            // 8192
#define OFF_MG     (OFF_CSUM + SZ_CSUM)      // 1024
#define OFF_W      (OFF_MG + C4 * 16)        // 1024
#define OFF_B      (OFF_W + C4 * 16)         // 1024
#define OFF_RM     (OFF_B + C4 * 16)         // fast-path rowmean: 128 floats
#define SZ_RM      (128 * 4)
#define OFF_RED    (OFF_RM + SZ_RM)
#define SZ_RED     (NW * 3 * 4)
#define OFF_IRED   (OFF_RED + SZ_RED)
#define SZ_IRED    (NW * 4)
#define SMEM_BYTES (OFF_IRED + SZ_IRED)      // 142976 B < 160 KiB

__device__ __forceinline__ float wave_reduce_sum(float x) {
#pragma unroll
    for (int off = 32; off > 0; off >>= 1) x += __shfl_xor(x, off);
    return x;
}

__global__ void __launch_bounds__(BLOCK, 2) gln_kernel(
    const float* __restrict__ s, const float* __restrict__ v,
    const float* __restrict__ weight, const float* __restrict__ bias,
    const int* __restrict__ splits,
    float* __restrict__ sout, float* __restrict__ vout)
{
    extern __shared__ char smem[];
    float4* s_lds     = (float4*)(smem + OFF_SLDS);
    float4* csum_part = (float4*)(smem + OFF_CSUM);   // [NW][C4]
    float4* mg4       = (float4*)(smem + OFF_MG);
    float4* w4s       = (float4*)(smem + OFF_W);
    float4* b4s       = (float4*)(smem + OFF_B);
    float*  rowmean_f = (float*)(smem + OFF_RM);      // fast path: 128 floats
    float*  rowmean_g = (float*)(smem + OFF_SLDS);    // generic path: RCAP floats (aliases s_lds)
    float*  red       = (float*)(smem + OFF_RED);     // [NW][3]
    int*    ired      = (int*)(smem + OFF_IRED);

    const int tid  = threadIdx.x;
    const int wv   = tid >> 6;
    const int lane = tid & 63;
    const int g    = blockIdx.x;

    // ---- start offset = prefix sum of splits[0..g) ----
    int acc = 0;
    for (int i = tid; i < g; i += BLOCK) acc += splits[i];
#pragma unroll
    for (int off = 32; off > 0; off >>= 1) acc += __shfl_xor(acc, off);
    if (lane == 0) ired[wv] = acc;
    if (wv == 0) {
        w4s[lane] = ((const float4*)weight)[lane];
        b4s[lane] = ((const float4*)bias)[lane];
    }
    __syncthreads();
    int start = 0;
#pragma unroll
    for (int i = 0; i < NW; i++) start += ired[i];
    const int cnt = splits[g];
    if (cnt <= 0) return;
    const float inv_cnt  = 1.0f / (float)cnt;
    const float inv_C    = 1.0f / (float)CCH;
    const float inv_cntC = inv_cnt * inv_C;

    const float4* s4p = (const float4*)s;
    const float4* v4p = (const float4*)v;

    const bool fast = (cnt == NW * RPW);

    // ---- pass A ----
    float4 colsum = make_float4(0.f, 0.f, 0.f, 0.f);
    float sumsq = 0.f, rs2 = 0.f, vn = 0.f;
    float4 vreg[3 * RPW];                 // v held in registers across the barrier (fast path)

    if (fast) {
        const int rbase = start + wv * RPW;

        // v: 48 independent loads -> held registers. Read ONCE from HBM, never again.
#pragma unroll
        for (int k = 0; k < RPW; k++) {
            const size_t vb = (size_t)(rbase + k) * (3 * C4) + lane;
            vreg[3 * k + 0] = v4p[vb];
            vreg[3 * k + 1] = v4p[vb + C4];
            vreg[3 * k + 2] = v4p[vb + 2 * C4];
        }
        float vn0 = 0.f, vn1 = 0.f, vn2 = 0.f, vn3 = 0.f;
#pragma unroll
        for (int k = 0; k < RPW; k++) {
            const float4 a  = vreg[3 * k + 0];
            const float4 bq = vreg[3 * k + 1];
            const float4 cq = vreg[3 * k + 2];
            vn0 += sqrtf(fmaf(a.x, a.x, fmaf(bq.x, bq.x, cq.x * cq.x)) + GLN_EPS);
            vn1 += sqrtf(fmaf(a.y, a.y, fmaf(bq.y, bq.y, cq.y * cq.y)) + GLN_EPS);
            vn2 += sqrtf(fmaf(a.z, a.z, fmaf(bq.z, bq.z, cq.z * cq.z)) + GLN_EPS);
            vn3 += sqrtf(fmaf(a.w, a.w, fmaf(bq.w, bq.w, cq.w * cq.w)) + GLN_EPS);
        }
        vn = (vn0 + vn1) + (vn2 + vn3);
        // pin: prevents the compiler from re-loading v in pass C instead of keeping regs
#pragma unroll
        for (int k = 0; k < 3 * RPW; k++) KEEP4(vreg[k]);

        // s: stream once from HBM -> LDS + stats. Pass C reads it from LDS.
        float prow[RPW];
#pragma unroll
        for (int k = 0; k < RPW; k++) {
            const size_t row = (size_t)(rbase + k);
            float4 sv = s4p[row * C4 + lane];
            s_lds[(wv * RPW + k) * C4 + lane] = sv;
            colsum.x += sv.x; colsum.y += sv.y; colsum.z += sv.z; colsum.w += sv.w;
            sumsq = fmaf(sv.x, sv.x, sumsq);
            sumsq = fmaf(sv.y, sv.y, sumsq);
            sumsq = fmaf(sv.z, sv.z, sumsq);
            sumsq = fmaf(sv.w, sv.w, sumsq);
            prow[k] = sv.x + sv.y + sv.z + sv.w;
        }
        // off-stream register-fed reduce (16 independent chains)
#pragma unroll
        for (int k = 0; k < RPW; k++) {
            float rsum = wave_reduce_sum(prow[k]);
            if (lane == 0) {
                rowmean_f[wv * RPW + k] = rsum * inv_C;
                rs2 = fmaf(rsum, rsum, rs2);
            }
        }
    } else {
        for (int rr = wv; rr < cnt; rr += NW) {
            const size_t row = (size_t)(start + rr);
            float4 sv = s4p[row * C4 + lane];
            colsum.x += sv.x; colsum.y += sv.y; colsum.z += sv.z; colsum.w += sv.w;
            sumsq = fmaf(sv.x, sv.x, sumsq);
            sumsq = fmaf(sv.y, sv.y, sumsq);
            sumsq = fmaf(sv.z, sv.z, sumsq);
            sumsq = fmaf(sv.w, sv.w, sumsq);
            float rsum = wave_reduce_sum(sv.x + sv.y + sv.z + sv.w);
            if (lane == 0) {
                rs2 = fmaf(rsum, rsum, rs2);
                if (rr < RCAP) rowmean_g[rr] = rsum * inv_C;
            }
            const size_t vb = row * (3 * C4) + lane;
            float4 a  = v4p[vb];
            float4 bq = v4p[vb + C4];
            float4 cq = v4p[vb + 2 * C4];
            vn += sqrtf(fmaf(a.x, a.x, fmaf(bq.x, bq.x, cq.x * cq.x)) + GLN_EPS);
            vn += sqrtf(fmaf(a.y, a.y, fmaf(bq.y, bq.y, cq.y * cq.y)) + GLN_EPS);
            vn += sqrtf(fmaf(a.z, a.z, fmaf(bq.z, bq.z, cq.z * cq.z)) + GLN_EPS);
            vn += sqrtf(fmaf(a.w, a.w, fmaf(bq.w, bq.w, cq.w * cq.w)) + GLN_EPS);
        }
    }
    csum_part[wv * C4 + lane] = colsum;

    // ---- block-reduce the three scalars ----
    float t0 = wave_reduce_sum(sumsq);
    float t2 = wave_reduce_sum(vn);
    if (lane == 0) { red[wv * 3 + 0] = t0; red[wv * 3 + 1] = rs2; red[wv * 3 + 2] = t2; }
    __syncthreads();

    // ---- wave 0: per-channel graph mean + final scalars ----
    if (wv == 0) {
        float sumsq_tot = 0.f, rs2_tot = 0.f, vn_tot = 0.f;
#pragma unroll
        for (int i = 0; i < NW; i++) {
            sumsq_tot += red[i * 3 + 0]; rs2_tot += red[i * 3 + 1]; vn_tot += red[i * 3 + 2];
        }
        float4 t = csum_part[lane];
#pragma unroll
        for (int i = 1; i < NW; i++) {
            t.x += csum_part[i * C4 + lane].x; t.y += csum_part[i * C4 + lane].y;
            t.z += csum_part[i * C4 + lane].z; t.w += csum_part[i * C4 + lane].w;
        }
        float gsum  = wave_reduce_sum(t.x + t.y + t.z + t.w);
        float gmean = gsum * inv_cntC;
        float4 mg;
        mg.x = t.x * inv_cnt - gmean;
        mg.y = t.y * inv_cnt - gmean;
        mg.z = t.z * inv_cnt - gmean;
        mg.w = t.w * inv_cnt - gmean;
        mg4[lane] = mg;
        float mg2 = wave_reduce_sum(mg.x * mg.x + mg.y * mg.y + mg.z * mg.z + mg.w * mg.w);
        if (lane == 0) {
            const float sum_s0sq = sumsq_tot - rs2_tot * inv_C;
            const float sum_cs2  = sum_s0sq - (float)cnt * mg2;
            const float var      = sum_cs2 * inv_cntC;
            red[0] = 1.0f / sqrtf(var + GLN_EPS);     // rstd
            red[1] = 1.0f / (vn_tot * inv_cntC);      // rvn
        }
    }
    __syncthreads();

    const float rstd = red[0];
    const float rvn  = red[1];

    // ---- pass C: ZERO global reads (fast path): sout from LDS, vout from registers ----
    float4 wl = w4s[lane];
    wl.x *= rstd; wl.y *= rstd; wl.z *= rstd; wl.w *= rstd;
    const float4 bl = b4s[lane];
    const float4 mg = mg4[lane];
    float4* so4 = (float4*)sout;
    float4* vo4 = (float4*)vout;

    if (fast) {
        const int rbase = start + wv * RPW;
#pragma unroll
        for (int k = 0; k < RPW; k++) {
            const size_t row = (size_t)(rbase + k);
            const float rmean = rowmean_f[wv * RPW + k];
            const float4 sv = s_lds[(wv * RPW + k) * C4 + lane];
            float4 o;
            o.x = fmaf(sv.x - rmean - mg.x, wl.x, bl.x);
            o.y = fmaf(sv.y - rmean - mg.y, wl.y, bl.y);
            o.z = fmaf(sv.z - rmean - mg.z, wl.z, bl.z);
            o.w = fmaf(sv.w - rmean - mg.w, wl.w, bl.w);
            so4[row * C4 + lane] = o;
        }
#pragma unroll
        for (int k = 0; k < RPW; k++) {
            const size_t vb = (size_t)(rbase + k) * (3 * C4) + lane;
            float4 a  = vreg[3 * k + 0];
            float4 bq = vreg[3 * k + 1];
            float4 cq = vreg[3 * k + 2];
            a.x  *= rvn; a.y  *= rvn; a.z  *= rvn; a.w  *= rvn;
            bq.x *= rvn; bq.y *= rvn; bq.z *= rvn; bq.w *= rvn;
            cq.x *= rvn; cq.y *= rvn; cq.z *= rvn; cq.w *= rvn;
            vo4[vb]          = a;
            vo4[vb + C4]     = bq;
            vo4[vb + 2 * C4] = cq;
        }
    } else {
        for (int rr = wv; rr < cnt; rr += NW) {
            const size_t row = (size_t)(start + rr);
            float4 sv = s4p[row * C4 + lane];
            float rmean;
            if (rr < RCAP) {
                rmean = rowmean_g[rr];
            } else {
                rmean = wave_reduce_sum(sv.x + sv.y + sv.z + sv.w) * inv_C;
            }
            float4 o;
            o.x = fmaf(sv.x - rmean - mg.x, wl.x, bl.x);
            o.y = fmaf(sv.y - rmean - mg.y, wl.y, bl.y);
            o.z = fmaf(sv.z - rmean - mg.z, wl.z, bl.z);
            o.w = fmaf(sv.w - rmean - mg.w, wl.w, bl.w);
            so4[row * C4 + lane] = o;

            const size_t vb = row * (3 * C4) + lane;
            float4 a  = v4p[vb];
            float4 bq = v4p[vb + C4];
            float4 cq = v4p[vb + 2 * C4];
            a.x  *= rvn; a.y  *= rvn; a.z  *= rvn; a.w  *= rvn;
            bq.x *= rvn; bq.y *= rvn; bq.z *= rvn; bq.w *= rvn;
            cq.x *= rvn; cq.y *= rvn; cq.z *= rvn; cq.w *= rvn;
            vo4[vb]          = a;
            vo4[vb + C4]     = bq;
            vo4[vb + 2 * C4] = cq;
        }
    }
}

extern "C" void kernel_launch(void* const* d_in, const int* in_sizes, int n_in,
                              void* d_out, int out_size, void* d_ws, size_t ws_size,
                              hipStream_t stream) {
    const float* s      = (const float*)d_in[0];
    const float* v      = (const float*)d_in[1];
    const float* w      = (const float*)d_in[2];
    const float* b      = (const float*)d_in[3];
    const int*   splits = (const int*)d_in[4];
    const int N = in_sizes[0] / CCH;
    const int G = in_sizes[4];
    float* out  = (float*)d_out;
    float* sout = out;
    float* vout = out + (size_t)N * CCH;

    static bool attr_set = false;
    if (!attr_set) {
        (void)hipFuncSetAttribute((const void*)gln_kernel,
                                  hipFuncAttributeMaxDynamicSharedMemorySize, SMEM_BYTES);
        attr_set = true;
    }
    gln_kernel<<<G, BLOCK, SMEM_BYTES, stream>>>(s, v, w, b, splits, sout, vout);
}

// Round 7
// 467.831 us; speedup vs baseline: 1.1814x; 1.1814x over previous
//
#include <hip/hip_runtime.h>
#include <math.h>

#define GLN_EPS 1e-6f
#define NW 16                   // waves per block (1024 threads)
#define BLOCK (NW * 64)
#define CCH 256                 // channels (fixed by problem)
#define C4 (CCH / 4)            // 64 float4 per row == one wave
#define RPW 8                   // rows per wave, fast path (cnt == NW*RPW == 128)
#define RCAP 2048               // rowmean cache rows (generic path; aliases s_lds)

// ---- dynamic-LDS carve (bytes) ----
#define OFF_SLDS   0
#define SZ_SLDS    (128 * C4 * 16)           // 131072: s tile [128 rows][64 float4]
#define OFF_CSUM   (OFF_SLDS + SZ_SLDS)
#define SZ_CSUM    (NW * C4 * 16)            // 16384
#define OFF_MG     (OFF_CSUM + SZ_CSUM)
#define OFF_W      (OFF_MG + C4 * 16)
#define OFF_B      (OFF_W + C4 * 16)
#define OFF_RM     (OFF_B + C4 * 16)         // fast-path rowmean: 128 floats
#define SZ_RM      (128 * 4)
#define OFF_RED    (OFF_RM + SZ_RM)
#define SZ_RED     (NW * 3 * 4)
#define OFF_IRED   (OFF_RED + SZ_RED)
#define SZ_IRED    (NW * 4)
#define SMEM_BYTES (OFF_IRED + SZ_IRED)      // ~151 KB < 160 KiB

__device__ __forceinline__ float wave_reduce_sum(float x) {
#pragma unroll
    for (int off = 32; off > 0; off >>= 1) x += __shfl_xor(x, off);
    return x;
}

__global__ void __launch_bounds__(BLOCK, 1) gln_kernel(
    const float* __restrict__ s, const float* __restrict__ v,
    const float* __restrict__ weight, const float* __restrict__ bias,
    const int* __restrict__ splits,
    float* __restrict__ sout, float* __restrict__ vout)
{
    extern __shared__ char smem[];
    float4* s_lds     = (float4*)(smem + OFF_SLDS);
    float4* csum_part = (float4*)(smem + OFF_CSUM);   // [NW][C4]
    float4* mg4       = (float4*)(smem + OFF_MG);
    float4* w4s       = (float4*)(smem + OFF_W);
    float4* b4s       = (float4*)(smem + OFF_B);
    float*  rowmean_f = (float*)(smem + OFF_RM);      // fast path: 128 floats
    float*  rowmean_g = (float*)(smem + OFF_SLDS);    // generic path (aliases s_lds)
    float*  red       = (float*)(smem + OFF_RED);     // [NW][3]
    int*    ired      = (int*)(smem + OFF_IRED);

    const int tid  = threadIdx.x;
    const int wv   = tid >> 6;
    const int lane = tid & 63;
    const int g    = blockIdx.x;

    // ---- start offset = prefix sum of splits[0..g) ----
    int acc = 0;
    for (int i = tid; i < g; i += BLOCK) acc += splits[i];
#pragma unroll
    for (int off = 32; off > 0; off >>= 1) acc += __shfl_xor(acc, off);
    if (lane == 0) ired[wv] = acc;
    if (wv == 0) {
        w4s[lane] = ((const float4*)weight)[lane];
        b4s[lane] = ((const float4*)bias)[lane];
    }
    __syncthreads();
    int start = 0;
#pragma unroll
    for (int i = 0; i < NW; i++) start += ired[i];
    const int cnt = splits[g];
    if (cnt <= 0) return;
    const float inv_cnt  = 1.0f / (float)cnt;
    const float inv_C    = 1.0f / (float)CCH;
    const float inv_cntC = inv_cnt * inv_C;

    const float4* s4p = (const float4*)s;
    const float4* v4p = (const float4*)v;

    const bool fast = (cnt == NW * RPW);

    // ---- pass A: pure load stream (zero cross-lane ops in-stream) ----
    float4 colsum = make_float4(0.f, 0.f, 0.f, 0.f);
    float sumsq = 0.f, rs2 = 0.f, vn = 0.f;

    if (fast) {
        const int rbase = start + wv * RPW;
        float prow[RPW];

        // s: HBM -> LDS + stats. Read ONCE from fabric; pass C uses LDS copy.
#pragma unroll
        for (int k = 0; k < RPW; k++) {
            const size_t row = (size_t)(rbase + k);
            float4 sv = s4p[row * C4 + lane];
            s_lds[(wv * RPW + k) * C4 + lane] = sv;
            colsum.x += sv.x; colsum.y += sv.y; colsum.z += sv.z; colsum.w += sv.w;
            sumsq = fmaf(sv.x, sv.x, sumsq);
            sumsq = fmaf(sv.y, sv.y, sumsq);
            sumsq = fmaf(sv.z, sv.z, sumsq);
            sumsq = fmaf(sv.w, sv.w, sumsq);
            prow[k] = sv.x + sv.y + sv.z + sv.w;
        }
        // v: lane-local accumulate (vn_tot is a flat sum; no per-row reduce)
        float vn0 = 0.f, vn1 = 0.f, vn2 = 0.f, vn3 = 0.f;
#pragma unroll 4
        for (int k = 0; k < RPW; k++) {
            const size_t vb = (size_t)(rbase + k) * (3 * C4) + lane;
            float4 a  = v4p[vb];
            float4 bq = v4p[vb + C4];
            float4 cq = v4p[vb + 2 * C4];
            vn0 += sqrtf(fmaf(a.x, a.x, fmaf(bq.x, bq.x, cq.x * cq.x)) + GLN_EPS);
            vn1 += sqrtf(fmaf(a.y, a.y, fmaf(bq.y, bq.y, cq.y * cq.y)) + GLN_EPS);
            vn2 += sqrtf(fmaf(a.z, a.z, fmaf(bq.z, bq.z, cq.z * cq.z)) + GLN_EPS);
            vn3 += sqrtf(fmaf(a.w, a.w, fmaf(bq.w, bq.w, cq.w * cq.w)) + GLN_EPS);
        }
        vn = (vn0 + vn1) + (vn2 + vn3);

        // off-stream: RPW independent register-fed shuffle chains
#pragma unroll
        for (int k = 0; k < RPW; k++) {
            float rsum = wave_reduce_sum(prow[k]);
            if (lane == 0) {
                rowmean_f[wv * RPW + k] = rsum * inv_C;
                rs2 = fmaf(rsum, rsum, rs2);
            }
        }
    } else {
        for (int rr = wv; rr < cnt; rr += NW) {
            const size_t row = (size_t)(start + rr);
            float4 sv = s4p[row * C4 + lane];
            colsum.x += sv.x; colsum.y += sv.y; colsum.z += sv.z; colsum.w += sv.w;
            sumsq = fmaf(sv.x, sv.x, sumsq);
            sumsq = fmaf(sv.y, sv.y, sumsq);
            sumsq = fmaf(sv.z, sv.z, sumsq);
            sumsq = fmaf(sv.w, sv.w, sumsq);
            float rsum = wave_reduce_sum(sv.x + sv.y + sv.z + sv.w);
            if (lane == 0) {
                rs2 = fmaf(rsum, rsum, rs2);
                if (rr < RCAP) rowmean_g[rr] = rsum * inv_C;
            }
            const size_t vb = row * (3 * C4) + lane;
            float4 a  = v4p[vb];
            float4 bq = v4p[vb + C4];
            float4 cq = v4p[vb + 2 * C4];
            vn += sqrtf(fmaf(a.x, a.x, fmaf(bq.x, bq.x, cq.x * cq.x)) + GLN_EPS);
            vn += sqrtf(fmaf(a.y, a.y, fmaf(bq.y, bq.y, cq.y * cq.y)) + GLN_EPS);
            vn += sqrtf(fmaf(a.z, a.z, fmaf(bq.z, bq.z, cq.z * cq.z)) + GLN_EPS);
            vn += sqrtf(fmaf(a.w, a.w, fmaf(bq.w, bq.w, cq.w * cq.w)) + GLN_EPS);
        }
    }
    csum_part[wv * C4 + lane] = colsum;

    // ---- block-reduce the three scalars ----
    float t0 = wave_reduce_sum(sumsq);
    float t2 = wave_reduce_sum(vn);
    if (lane == 0) { red[wv * 3 + 0] = t0; red[wv * 3 + 1] = rs2; red[wv * 3 + 2] = t2; }
    __syncthreads();

    // ---- wave 0: per-channel graph mean + final scalars ----
    if (wv == 0) {
        float sumsq_tot = 0.f, rs2_tot = 0.f, vn_tot = 0.f;
#pragma unroll
        for (int i = 0; i < NW; i++) {
            sumsq_tot += red[i * 3 + 0]; rs2_tot += red[i * 3 + 1]; vn_tot += red[i * 3 + 2];
        }
        float4 t = csum_part[lane];
#pragma unroll
        for (int i = 1; i < NW; i++) {
            t.x += csum_part[i * C4 + lane].x; t.y += csum_part[i * C4 + lane].y;
            t.z += csum_part[i * C4 + lane].z; t.w += csum_part[i * C4 + lane].w;
        }
        float gsum  = wave_reduce_sum(t.x + t.y + t.z + t.w);
        float gmean = gsum * inv_cntC;
        float4 mg;
        mg.x = t.x * inv_cnt - gmean;
        mg.y = t.y * inv_cnt - gmean;
        mg.z = t.z * inv_cnt - gmean;
        mg.w = t.w * inv_cnt - gmean;
        mg4[lane] = mg;
        float mg2 = wave_reduce_sum(mg.x * mg.x + mg.y * mg.y + mg.z * mg.z + mg.w * mg.w);
        if (lane == 0) {
            const float sum_s0sq = sumsq_tot - rs2_tot * inv_C;
            const float sum_cs2  = sum_s0sq - (float)cnt * mg2;
            const float var      = sum_cs2 * inv_cntC;
            red[0] = 1.0f / sqrtf(var + GLN_EPS);     // rstd
            red[1] = 1.0f / (vn_tot * inv_cntC);      // rvn
        }
    }
    __syncthreads();

    const float rstd = red[0];
    const float rvn  = red[1];

    // ---- pass C: sout from LDS (no global reads), then v L3 re-read + scale ----
    float4 wl = w4s[lane];
    wl.x *= rstd; wl.y *= rstd; wl.z *= rstd; wl.w *= rstd;
    const float4 bl = b4s[lane];
    const float4 mg = mg4[lane];
    float4* so4 = (float4*)sout;
    float4* vo4 = (float4*)vout;

    if (fast) {
        const int rbase = start + wv * RPW;
#pragma unroll
        for (int k = 0; k < RPW; k++) {
            const size_t row = (size_t)(rbase + k);
            const float rmean = rowmean_f[wv * RPW + k];
            const float4 sv = s_lds[(wv * RPW + k) * C4 + lane];
            float4 o;
            o.x = fmaf(sv.x - rmean - mg.x, wl.x, bl.x);
            o.y = fmaf(sv.y - rmean - mg.y, wl.y, bl.y);
            o.z = fmaf(sv.z - rmean - mg.z, wl.z, bl.z);
            o.w = fmaf(sv.w - rmean - mg.w, wl.w, bl.w);
            so4[row * C4 + lane] = o;
        }
#pragma unroll 2
        for (int k = 0; k < RPW; k++) {
            const size_t vb = (size_t)(rbase + k) * (3 * C4) + lane;
            float4 a  = v4p[vb];
            float4 bq = v4p[vb + C4];
            float4 cq = v4p[vb + 2 * C4];
            a.x  *= rvn; a.y  *= rvn; a.z  *= rvn; a.w  *= rvn;
            bq.x *= rvn; bq.y *= rvn; bq.z *= rvn; bq.w *= rvn;
            cq.x *= rvn; cq.y *= rvn; cq.z *= rvn; cq.w *= rvn;
            vo4[vb]          = a;
            vo4[vb + C4]     = bq;
            vo4[vb + 2 * C4] = cq;
        }
    } else {
        for (int rr = wv; rr < cnt; rr += NW) {
            const size_t row = (size_t)(start + rr);
            float4 sv = s4p[row * C4 + lane];
            float rmean;
            if (rr < RCAP) {
                rmean = rowmean_g[rr];
            } else {
                rmean = wave_reduce_sum(sv.x + sv.y + sv.z + sv.w) * inv_C;
            }
            float4 o;
            o.x = fmaf(sv.x - rmean - mg.x, wl.x, bl.x);
            o.y = fmaf(sv.y - rmean - mg.y, wl.y, bl.y);
            o.z = fmaf(sv.z - rmean - mg.z, wl.z, bl.z);
            o.w = fmaf(sv.w - rmean - mg.w, wl.w, bl.w);
            so4[row * C4 + lane] = o;

            const size_t vb = row * (3 * C4) + lane;
            float4 a  = v4p[vb];
            float4 bq = v4p[vb + C4];
            float4 cq = v4p[vb + 2 * C4];
            a.x  *= rvn; a.y  *= rvn; a.z  *= rvn; a.w  *= rvn;
            bq.x *= rvn; bq.y *= rvn; bq.z *= rvn; bq.w *= rvn;
            cq.x *= rvn; cq.y *= rvn; cq.z *= rvn; cq.w *= rvn;
            vo4[vb]          = a;
            vo4[vb + C4]     = bq;
            vo4[vb + 2 * C4] = cq;
        }
    }
}

extern "C" void kernel_launch(void* const* d_in, const int* in_sizes, int n_in,
                              void* d_out, int out_size, void* d_ws, size_t ws_size,
                              hipStream_t stream) {
    const float* s      = (const float*)d_in[0];
    const float* v      = (const float*)d_in[1];
    const float* w      = (const float*)d_in[2];
    const float* b      = (const float*)d_in[3];
    const int*   splits = (const int*)d_in[4];
    const int N = in_sizes[0] / CCH;
    const int G = in_sizes[4];
    float* out  = (float*)d_out;
    float* sout = out;
    float* vout = out + (size_t)N * CCH;

    static bool attr_set = false;
    if (!attr_set) {
        (void)hipFuncSetAttribute((const void*)gln_kernel,
                                  hipFuncAttributeMaxDynamicSharedMemorySize, SMEM_BYTES);
        attr_set = true;
    }
    gln_kernel<<<G, BLOCK, SMEM_BYTES, stream>>>(s, v, w, b, splits, sout, vout);
}